// Round 7
// baseline (348.589 us; speedup 1.0000x reference)
//
#include <hip/hip_runtime.h>
#include <hip/hip_bf16.h>

// GroupQueryAttention: B=2,S=2048,E=768,H=12,G=4,D=64,T=512
// R7: weight pre-combination. ki = key @ (Wk_in Wk)^T + (Wk_in bk + bk_in),
//     same for q,v chains -> the qkv projection pass is deleted entirely.
//     5 launches: prep | combine_gemm | proj_gemm | attn | out_gemm.

typedef __attribute__((ext_vector_type(8))) short short8;
typedef __attribute__((ext_vector_type(4))) float floatx4;

static __device__ __forceinline__ short f2bf(float f) {
    __bf16 b = (__bf16)f;              // fptrunc RNE -> HW cvt
    return __builtin_bit_cast(short, b);
}
static __device__ __forceinline__ short8 f8_to_bf8(floatx4 f0, floatx4 f1) {
    short8 s;
    s[0]=f2bf(f0[0]); s[1]=f2bf(f0[1]); s[2]=f2bf(f0[2]); s[3]=f2bf(f0[3]);
    s[4]=f2bf(f1[0]); s[5]=f2bf(f1[1]); s[6]=f2bf(f1[2]); s[7]=f2bf(f1[3]);
    return s;
}
static __device__ __forceinline__ void gload_lds16(const short* g, short* l) {
    __builtin_amdgcn_global_load_lds(
        (const __attribute__((address_space(1))) unsigned int*)g,
        (__attribute__((address_space(3))) unsigned int*)l, 16, 0, 0);
}

// ---------------------------------------------------------------------------
// prep: [0,432) transpose-cast Wqg/Wk/Wv -> WTo bf16 (64x64 tiles via LDS);
//       [432,1584) cast Wout -> bf16; [1584,6192) cast q,k,v -> bf16;
//       [6192,6240) combined biases b2[chain,g] = Wx_in[g] @ bx + bx_in.
// ---------------------------------------------------------------------------
__global__ __launch_bounds__(256) void prep(
    const float* query, const float* key, const float* value,
    const float* Wqg, const float* Wk, const float* Wv, const float* Wout,
    const float* Wq_in, const float* Wk_in, const float* Wv_in,
    const float* bqg, const float* bk, const float* bv,
    const float* bq_in, const float* bk_in, const float* bv_in,
    short* WTo, short* Woutbf, short* qkvbf, float* b2)
{
    const int x = blockIdx.x, tid = threadIdx.x;
    const long U = 589824L;
    if (x < 432) {                     // transpose-cast outer weights
        __shared__ float T[64][65];
        const int mat = x / 144, t = x % 144, tr = t / 12, tc = t % 12;
        const float* src = (mat == 0) ? Wqg : (mat == 1) ? Wk : Wv;
        short* dst = WTo + (long)mat * U;
        const int r = tid >> 2, c0 = (tid & 3) << 4;
        const float* sp = src + (long)(tr * 64 + r) * 768 + tc * 64 + c0;
#pragma unroll
        for (int j = 0; j < 4; j++)
            *(floatx4*)&T[r][c0 + j * 4] = *(const floatx4*)(sp + j * 4);
        __syncthreads();
        short tmp[16];
#pragma unroll
        for (int j = 0; j < 16; j++) tmp[j] = f2bf(T[c0 + j][r]);
        short* dp = dst + (long)(tc * 64 + r) * 768 + tr * 64 + c0;
        *(short8*)dp = *(short8*)&tmp[0];
        *(short8*)(dp + 8) = *(short8*)&tmp[8];
    } else if (x < 1584) {             // cast Wout (4U elems)
        const long i = (long)(x - 432) * 2048 + tid * 8;
        floatx4 f0 = *(const floatx4*)(Wout + i);
        floatx4 f1 = *(const floatx4*)(Wout + i + 4);
        *(short8*)(Woutbf + i) = f8_to_bf8(f0, f1);
    } else if (x < 6192) {             // cast q,k,v inputs (3 x 3145728)
        const long i = (long)(x - 1584) * 2048 + tid * 8;
        const int which = (int)(i / 3145728L);
        const float* src = (which == 0) ? query : (which == 1) ? key : value;
        const long off = i - (long)which * 3145728L;
        floatx4 f0 = *(const floatx4*)(src + off);
        floatx4 f1 = *(const floatx4*)(src + off + 4);
        *(short8*)(qkvbf + i) = f8_to_bf8(f0, f1);
    } else {                           // combined biases, 48 blocks of 192 rows
        const int idx = x - 6192, cg = idx >> 2, qtr = idx & 3;
        const int chain = cg >> 2, g = cg & 3;
        const float* Wi = ((chain == 0) ? Wq_in : (chain == 1) ? Wk_in : Wv_in) + (long)g * U;
        const float* bo = (chain == 0) ? bqg : (chain == 1) ? bk : bv;
        const float* bi = ((chain == 0) ? bq_in : (chain == 1) ? bk_in : bv_in) + g * 768;
        if (tid < 192) {
            const int row = qtr * 192 + tid;
            float acc = 0.f;
            for (int e = 0; e < 768; e += 4) {
                floatx4 w = *(const floatx4*)(Wi + (long)row * 768 + e);
                floatx4 bb = *(const floatx4*)(bo + e);
                acc += w[0]*bb[0] + w[1]*bb[1] + w[2]*bb[2] + w[3]*bb[3];
            }
            b2[cg * 768 + row] = acc + bi[row];
        }
    }
}

// ---------------------------------------------------------------------------
// Shared GEMM core: C = A @ W^T + bias, K=768, 128x128 tile, BK=64,
// 4 waves x 64x64 (4x4 MFMA 16x16x32 bf16). W via global_load_lds with XOR
// chunk swizzle; A same (bf16) or fp32->cvt->ds_write (A_IS_F32, LDS-slot
// swizzled). CMODE: 0 bf16 C, 2 f32 C. BIAS_MODE: 0 col, 1 row, 2 none.
// ---------------------------------------------------------------------------
template<int A_IS_F32, int CMODE, int BIAS_MODE>
static __device__ __forceinline__ void gemm_core(
    const void* __restrict__ Av, const short* __restrict__ Wb,
    const float* __restrict__ bp, void* __restrict__ Cv,
    int lda, int ldc, int bm, int bn, short* As, short* Bs)
{
    const int tid = threadIdx.x, lane = tid & 63, w = tid >> 6;
    const int wm = w & 1, wn = w >> 1;
    const int qr = lane >> 4, lc = lane & 15, x7 = lc & 7;
    const int srow = tid >> 3, schunk = tid & 7, sx = srow & 7;

    const short* Wt = Wb + (long)(bn * 128) * 768;

    floatx4 acc[4][4];
#pragma unroll
    for (int mi = 0; mi < 4; mi++)
#pragma unroll
        for (int ni = 0; ni < 4; ni++) acc[mi][ni] = (floatx4){0.f, 0.f, 0.f, 0.f};

    for (int k0 = 0; k0 < 768; k0 += 64) {
        __syncthreads();
#pragma unroll
        for (int p = 0; p < 4; p++) {
            const int row = p * 32 + srow;
            if (A_IS_F32) {
                const float* ap = (const float*)Av + (long)(bm * 128 + row) * lda + k0 + schunk * 8;
                floatx4 f0 = *(const floatx4*)ap;
                floatx4 f1 = *(const floatx4*)(ap + 4);
                *(short8*)&As[row * 64 + ((schunk ^ sx) << 3)] = f8_to_bf8(f0, f1);
            } else {
                gload_lds16((const short*)Av + (long)(bm * 128 + row) * lda + k0 + ((schunk ^ sx) << 3),
                            &As[(p * 32 + w * 8) * 64]);
            }
            gload_lds16(Wt + (long)row * 768 + k0 + ((schunk ^ sx) << 3),
                        &Bs[(p * 32 + w * 8) * 64]);
        }
        __syncthreads();
#pragma unroll
        for (int ks = 0; ks < 64; ks += 32) {
            const int c0 = (ks >> 3) + qr;
            const int slot = ((c0 ^ x7) << 3);
            short8 af[4], bfr[4];
#pragma unroll
            for (int mi = 0; mi < 4; mi++)
                af[mi] = *(const short8*)&As[(wm * 64 + mi * 16 + lc) * 64 + slot];
#pragma unroll
            for (int ni = 0; ni < 4; ni++)
                bfr[ni] = *(const short8*)&Bs[(wn * 64 + ni * 16 + lc) * 64 + slot];
#pragma unroll
            for (int mi = 0; mi < 4; mi++)
#pragma unroll
                for (int ni = 0; ni < 4; ni++)
                    acc[mi][ni] = __builtin_amdgcn_mfma_f32_16x16x32_bf16(
                        af[mi], bfr[ni], acc[mi][ni], 0, 0, 0);
        }
    }

    // C/D layout: col=lane&15, row=quad*4+reg
#pragma unroll
    for (int ni = 0; ni < 4; ni++) {
        const int gcol = bn * 128 + wn * 64 + ni * 16 + lc;
        const float bcol = (BIAS_MODE == 0) ? bp[gcol] : 0.f;
#pragma unroll
        for (int mi = 0; mi < 4; mi++) {
#pragma unroll
            for (int r = 0; r < 4; r++) {
                const int grow = bm * 128 + wm * 64 + mi * 16 + qr * 4 + r;
                const float bb = (BIAS_MODE == 1) ? bp[grow] : bcol;
                const float v = acc[mi][ni][r] + bb;
                if (CMODE == 0)
                    ((short*)Cv)[(long)grow * ldc + gcol] = f2bf(v);
                else
                    ((float*)Cv)[(long)grow * ldc + gcol] = v;
            }
        }
    }
}

// combine: W2[chain,g] = Wx_in[g] (fp32) @ WTo[chain]^T, bf16 out, no bias.
// grid 576: xcd = x&7 gets cg = xcd (slot<36) or 8+xcd (xcd<4); 144 idle.
__global__ __launch_bounds__(256) void combine_gemm(
    const float* Wq_in, const float* Wk_in, const float* Wv_in,
    const short* WTo, short* W2)
{
    const int xcd = blockIdx.x & 7, slot = blockIdx.x >> 3;
    int cg;
    if (slot < 36) cg = xcd;
    else { if (xcd >= 4) return; cg = 8 + xcd; }
    const int tile = slot % 36, chain = cg / 4, g = cg & 3;
    __shared__ short As[128 * 64];
    __shared__ short Bs[128 * 64];
    const float* A = ((chain == 0) ? Wq_in : (chain == 1) ? Wk_in : Wv_in) + (long)g * 589824;
    gemm_core<1, 0, 2>(A, WTo + (long)chain * 589824, nullptr,
                       W2 + (long)cg * 589824, 768, 768, tile / 6, tile % 6, As, Bs);
}

// proj GEMMs fused: grid 1728. XCD k owns z=(b,g)=k; slots: ki 96 | vt 96 | qi 24.
__global__ __launch_bounds__(256) void proj_gemm(
    const short* qkvbf, const short* W2, const float* b2,
    short* kiB, short* vtB, short* qiB)
{
    __shared__ short As[128 * 64];
    __shared__ short Bs[128 * 64];
    const int xcd = blockIdx.x & 7, slot = blockIdx.x >> 3;
    const int z = xcd, b = z >> 2, g = z & 3;
    const short* q_bf = qkvbf;
    const short* k_bf = qkvbf + 3145728L;
    const short* v_bf = qkvbf + 6291456L;
    if (slot < 96) {          // ki[b,g,s,f] = k @ W2k[g]^T + b2k[g]
        gemm_core<0, 0, 0>(k_bf + (long)b * 1572864, W2 + (long)(4 + g) * 589824,
                           b2 + (4 + g) * 768, kiB + (long)z * 1572864,
                           768, 768, slot / 6, slot % 6, As, Bs);
    } else if (slot < 192) {  // vt[b,g,f,s] = W2v[g] @ v^T + b2v[g] (row bias)
        const int s2 = slot - 96;
        gemm_core<0, 0, 1>(W2 + (long)(8 + g) * 589824, v_bf + (long)b * 1572864,
                           b2 + (8 + g) * 768, vtB + (long)z * 1572864,
                           768, 2048, s2 / 16, s2 % 16, As, Bs);
    } else {                  // qi: M=512, interleaved gather (token = t*4+g)
        const int s3 = slot - 192;
        gemm_core<0, 0, 0>(q_bf + (long)b * 1572864 + g * 768, W2 + (long)g * 589824,
                           b2 + g * 768, qiB + (long)z * 393216,
                           3072, 768, s3 / 6, s3 % 6, As, Bs);
    }
}

// out projection: grid 192. XCD k owns z=k. fp32 C scattered (ldc=3072).
__global__ __launch_bounds__(256) void out_gemm(
    const short* ctxB, const short* Woutbf, const float* bout, float* out)
{
    __shared__ short As[128 * 64];
    __shared__ short Bs[128 * 64];
    const int xcd = blockIdx.x & 7, slot = blockIdx.x >> 3;
    const int z = xcd, b = z >> 2, g = z & 3;
    gemm_core<0, 2, 0>(ctxB + (long)z * 393216, Woutbf + (long)g * 589824,
                       bout + g * 768, out + (long)b * 1572864 + g * 768,
                       768, 3072, slot / 6, slot % 6, As, Bs);
}

// ---------------------------------------------------------------------------
// Flash attention (R4 structure). 1 WG = 64 q-rows of one (b,g,h).
// Double-buffered 64-wide K/V tiles; no-max softmax; MFMA ones-column l.
// blockIdx = tile*96 + head; 96 % 8 == 0 so a head's 8 tiles share an XCD.
// ---------------------------------------------------------------------------
__global__ __launch_bounds__(256) void attn_kernel(
    const short* __restrict__ qi, const short* __restrict__ ki,
    const short* __restrict__ vt, short* __restrict__ ctx)
{
    __shared__ short Kt[2][64 * 64];
    __shared__ short Vt[2][64 * 64];
    __shared__ short Ps[4][16 * 64];

    const int tid = threadIdx.x, lane = tid & 63, w = tid >> 6;
    const int qr = lane >> 4, lc = lane & 15, x7 = lc & 7;
    const int headid = blockIdx.x % 96;
    const int tile = blockIdx.x / 96;
    const int h = headid % 12, bg = headid / 12;

    const short* qp = qi + ((long)bg * 512 + tile * 64 + w * 16 + lc) * 768 + h * 64 + qr * 8;
    const short8 aq0 = *(const short8*)qp;
    const short8 aq1 = *(const short8*)(qp + 32);

    const short one = (lc == 0) ? (short)0x3F80 : (short)0;   // bf16 1.0
    const short8 onesv = (short8){one, one, one, one, one, one, one, one};

    floatx4 cacc[4], lacc = (floatx4){0.f, 0.f, 0.f, 0.f};
#pragma unroll
    for (int dc = 0; dc < 4; dc++) cacc[dc] = (floatx4){0.f, 0.f, 0.f, 0.f};

    const int srow = lane >> 3, schk = lane & 7, swz = schk ^ srow;
    const short* kgb = ki + ((long)bg * 2048) * 768 + h * 64;
    const short* vgb = vt + ((long)(bg * 768 + h * 64)) * 2048;

#pragma unroll
    for (int inst = 0; inst < 2; inst++) {
        const int rk = w * 16 + inst * 8 + srow;
        gload_lds16(kgb + (long)rk * 768 + swz * 8, &Kt[0][(w * 16 + inst * 8) * 64]);
        gload_lds16(vgb + (long)rk * 2048 + swz * 8, &Vt[0][(w * 16 + inst * 8) * 64]);
    }

    for (int it = 0; it < 32; it++) {
        const int cur = it & 1;
        __syncthreads();
        if (it < 31) {
            const int nxt = cur ^ 1, s0 = (it + 1) * 64;
#pragma unroll
            for (int inst = 0; inst < 2; inst++) {
                const int rk = w * 16 + inst * 8 + srow;
                gload_lds16(kgb + (long)(s0 + rk) * 768 + swz * 8,
                            &Kt[nxt][(w * 16 + inst * 8) * 64]);
                gload_lds16(vgb + (long)rk * 2048 + s0 + swz * 8,
                            &Vt[nxt][(w * 16 + inst * 8) * 64]);
            }
        }

        const short* Kb = &Kt[cur][0];
        const short* Vb = &Vt[cur][0];

        floatx4 sv[4];
#pragma unroll
        for (int ss = 0; ss < 4; ss++) {
            const short* kr = Kb + (ss * 16 + lc) * 64;
            short8 b0 = *(const short8*)(kr + ((qr ^ x7) << 3));
            short8 b1 = *(const short8*)(kr + (((4 + qr) ^ x7) << 3));
            floatx4 t = (floatx4){0.f, 0.f, 0.f, 0.f};
            t = __builtin_amdgcn_mfma_f32_16x16x32_bf16(aq0, b0, t, 0, 0, 0);
            t = __builtin_amdgcn_mfma_f32_16x16x32_bf16(aq1, b1, t, 0, 0, 0);
            sv[ss] = t;
        }

        // p = exp2(s * 0.125*log2e) -> P scratch (swizzled)
        short* ps = &Ps[w][0];
#pragma unroll
        for (int ss = 0; ss < 4; ss++) {
            const int cch = ss * 2 + (lc >> 3);
#pragma unroll
            for (int r = 0; r < 4; r++) {
                const int m = qr * 4 + r;
                ps[m * 64 + ((cch ^ (m & 7)) << 3) + x7] =
                    f2bf(__builtin_amdgcn_exp2f(sv[ss][r] * 0.18033688f));
            }
        }
        asm volatile("s_waitcnt lgkmcnt(0)" ::: "memory");
        const short8 ap0 = *(const short8*)&ps[lc * 64 + ((qr ^ x7) << 3)];
        const short8 ap1 = *(const short8*)&ps[lc * 64 + (((4 + qr) ^ x7) << 3)];

        lacc = __builtin_amdgcn_mfma_f32_16x16x32_bf16(ap0, onesv, lacc, 0, 0, 0);
        lacc = __builtin_amdgcn_mfma_f32_16x16x32_bf16(ap1, onesv, lacc, 0, 0, 0);
#pragma unroll
        for (int dc = 0; dc < 4; dc++) {
            const short* vr = Vb + (dc * 16 + lc) * 64;
            short8 bv0 = *(const short8*)(vr + ((qr ^ x7) << 3));
            short8 bv1 = *(const short8*)(vr + (((4 + qr) ^ x7) << 3));
            cacc[dc] = __builtin_amdgcn_mfma_f32_16x16x32_bf16(ap0, bv0, cacc[dc], 0, 0, 0);
            cacc[dc] = __builtin_amdgcn_mfma_f32_16x16x32_bf16(ap1, bv1, cacc[dc], 0, 0, 0);
        }
    }

    float linv[4];
#pragma unroll
    for (int r = 0; r < 4; r++)
        linv[r] = 1.f / __shfl(lacc[r], lane & 48);
    short* cp = ctx + ((long)bg * 512 + tile * 64 + w * 16) * 768 + h * 64;
#pragma unroll
    for (int dc = 0; dc < 4; dc++)
#pragma unroll
        for (int r = 0; r < 4; r++)
            cp[(qr * 4 + r) * 768 + dc * 16 + lc] = f2bf(cacc[dc][r] * linv[r]);
}

// ---------------------------------------------------------------------------
extern "C" void kernel_launch(void* const* d_in, const int* in_sizes, int n_in,
                              void* d_out, int out_size, void* d_ws, size_t ws_size,
                              hipStream_t stream) {
    const float* query = (const float*)d_in[0];
    const float* key   = (const float*)d_in[1];
    const float* value = (const float*)d_in[2];
    const float* Wqg = (const float*)d_in[3];  const float* bqg = (const float*)d_in[4];
    const float* Wk  = (const float*)d_in[5];  const float* bk  = (const float*)d_in[6];
    const float* Wv  = (const float*)d_in[7];  const float* bv  = (const float*)d_in[8];
    const float* Wq_in = (const float*)d_in[9];  const float* bq_in = (const float*)d_in[10];
    const float* Wk_in = (const float*)d_in[11]; const float* bk_in = (const float*)d_in[12];
    const float* Wv_in = (const float*)d_in[13]; const float* bv_in = (const float*)d_in[14];
    const float* Wout  = (const float*)d_in[15]; const float* bout  = (const float*)d_in[16];
    float* out = (float*)d_out;

    // workspace (shorts), ~98 MB:
    short* ws     = (short*)d_ws;
    const long U  = 589824L;
    short* WTo    = ws;                   // 3U transposed outer weights
    short* Woutbf = ws + 3 * U;           // 4U
    short* W2     = ws + 7 * U;           // 12U combined weights (q4|k4|v4)
    short* qkvbf  = ws + 11206656L;       // q|k|v bf16, 3 x 3145728
    short* qiB    = ws + 20643840L;       // 3145728
    short* vtB    = ws + 23789568L;       // 12582912
    short* kiB    = ws + 36372480L;       // 12582912, end 48955392
    short* ctxB   = ws + 11206656L;       // aliases qkvbf (dead after proj)
    float* b2     = (float*)(ws + 48955392L);  // 12*768 combined biases

    dim3 blk(256);

    prep<<<dim3(6240), blk, 0, stream>>>(
        query, key, value, Wqg, Wk, Wv, Wout, Wq_in, Wk_in, Wv_in,
        bqg, bk, bv, bq_in, bk_in, bv_in, WTo, Woutbf, qkvbf, b2);

    combine_gemm<<<dim3(576), blk, 0, stream>>>(Wq_in, Wk_in, Wv_in, WTo, W2);

    proj_gemm<<<dim3(1728), blk, 0, stream>>>(qkvbf, W2, b2, kiB, vtB, qiB);

    attn_kernel<<<dim3(768), blk, 0, stream>>>(qiB, kiB, vtB, ctxB);

    out_gemm<<<dim3(192), blk, 0, stream>>>(ctxB, Woutbf, bout, out);
}

// Round 8
// 298.476 us; speedup vs baseline: 1.1679x; 1.1679x over previous
//
#include <hip/hip_runtime.h>
#include <hip/hip_bf16.h>

// GroupQueryAttention: B=2,S=2048,E=768,H=12,G=4,D=64,T=512
// R8 = R6 pipeline (combine reverted) + double-buffered K-loop in the bf16
//     GEMMs (mid/out): 1 barrier/iter, global_load_lds for tile k+1 issued
//     before computing tile k -> the ~900-cyc staging drain is overlapped.

typedef __attribute__((ext_vector_type(8))) short short8;
typedef __attribute__((ext_vector_type(4))) float floatx4;

static __device__ __forceinline__ short f2bf(float f) {
    __bf16 b = (__bf16)f;              // fptrunc RNE -> HW cvt
    return __builtin_bit_cast(short, b);
}
static __device__ __forceinline__ short8 f8_to_bf8(floatx4 f0, floatx4 f1) {
    short8 s;
    s[0]=f2bf(f0[0]); s[1]=f2bf(f0[1]); s[2]=f2bf(f0[2]); s[3]=f2bf(f0[3]);
    s[4]=f2bf(f1[0]); s[5]=f2bf(f1[1]); s[6]=f2bf(f1[2]); s[7]=f2bf(f1[3]);
    return s;
}
static __device__ __forceinline__ void gload_lds16(const short* g, short* l) {
    __builtin_amdgcn_global_load_lds(
        (const __attribute__((address_space(1))) unsigned int*)g,
        (__attribute__((address_space(3))) unsigned int*)l, 16, 0, 0);
}

// ---------------------------------------------------------------------------
// weights fp32->bf16 (7 tensors, 19*768^2 elems contiguous dst)
// ---------------------------------------------------------------------------
__global__ __launch_bounds__(256) void cast_w(
    const float* a0, const float* a1, const float* a2, const float* a3,
    const float* a4, const float* a5, const float* a6, short* dst)
{
    const long U = 589824L;
    const float* ptrs[7] = {a0,a1,a2,a3,a4,a5,a6};
    const long starts[8] = {0, U, 2*U, 3*U, 7*U, 11*U, 15*U, 19*U};
    long i = (long)blockIdx.x * 2048 + (long)threadIdx.x * 8;
    int t = 0;
    while (t < 6 && i >= starts[t + 1]) t++;
    const float* s = ptrs[t] + (i - starts[t]);
    floatx4 f0 = *(const floatx4*)s;
    floatx4 f1 = *(const floatx4*)(s + 4);
    *(short8*)(dst + i) = f8_to_bf8(f0, f1);
}

// ---------------------------------------------------------------------------
// MFMA compute + epilogue shared by both GEMM cores.
// C/D layout: col=lane&15, row=quad*4+reg.
// ---------------------------------------------------------------------------
#define GEMM_LANE_VARS                                                        \
    const int tid = threadIdx.x, lane = tid & 63, w = tid >> 6;               \
    const int wm = w & 1, wn = w >> 1;                                        \
    const int qr = lane >> 4, lc = lane & 15, x7 = lc & 7;                    \
    const int srow = tid >> 3, schunk = tid & 7, sx = srow & 7;

template<int CMODE, int BIAS_MODE>
static __device__ __forceinline__ void gemm_epilogue(
    floatx4 (&acc)[4][4], const float* bp, void* Cv, int ldc, int bm, int bn,
    int wm, int wn, int qr, int lc)
{
#pragma unroll
    for (int ni = 0; ni < 4; ni++) {
        const int gcol = bn * 128 + wn * 64 + ni * 16 + lc;
        const float bcol = (BIAS_MODE == 0) ? bp[gcol] : 0.f;
#pragma unroll
        for (int mi = 0; mi < 4; mi++) {
#pragma unroll
            for (int r = 0; r < 4; r++) {
                const int grow = bm * 128 + wm * 64 + mi * 16 + qr * 4 + r;
                const float bb = (BIAS_MODE == 1) ? bp[grow] : bcol;
                const float v = acc[mi][ni][r] + bb;
                if (CMODE == 0)
                    ((short*)Cv)[(long)grow * ldc + gcol] = f2bf(v);
                else
                    ((float*)Cv)[(long)grow * ldc + gcol] = v;
            }
        }
    }
}

static __device__ __forceinline__ void gemm_mfma_step(
    floatx4 (&acc)[4][4], const short* Ac, const short* Bc,
    int wm, int wn, int qr, int lc, int x7)
{
#pragma unroll
    for (int ks = 0; ks < 64; ks += 32) {
        const int c0 = (ks >> 3) + qr;
        const int slot = ((c0 ^ x7) << 3);
        short8 af[4], bfr[4];
#pragma unroll
        for (int mi = 0; mi < 4; mi++)
            af[mi] = *(const short8*)&Ac[(wm * 64 + mi * 16 + lc) * 64 + slot];
#pragma unroll
        for (int ni = 0; ni < 4; ni++)
            bfr[ni] = *(const short8*)&Bc[(wn * 64 + ni * 16 + lc) * 64 + slot];
#pragma unroll
        for (int mi = 0; mi < 4; mi++)
#pragma unroll
            for (int ni = 0; ni < 4; ni++)
                acc[mi][ni] = __builtin_amdgcn_mfma_f32_16x16x32_bf16(
                    af[mi], bfr[ni], acc[mi][ni], 0, 0, 0);
    }
}

// ---------------------------------------------------------------------------
// Double-buffered bf16 GEMM core: C = A @ W^T + bias, K=768, 128x128 tile,
// BK=64, 1 barrier/iter; tile k+1 staged (global_load_lds, XOR chunk swizzle)
// while tile k computes. As/Bs: 2 x 8192 shorts each (64 KB total LDS).
// ---------------------------------------------------------------------------
template<int CMODE, int BIAS_MODE>
static __device__ __forceinline__ void gemm_core_db(
    const short* __restrict__ A, const short* __restrict__ Wb,
    const float* __restrict__ bp, void* __restrict__ Cv,
    int lda, int ldc, int bm, int bn, short* As, short* Bs)
{
    GEMM_LANE_VARS
    const short* Ab = A + (long)(bm * 128) * lda;
    const short* Wt = Wb + (long)(bn * 128) * 768;
    const int gch = ((schunk ^ sx) << 3);

    floatx4 acc[4][4];
#pragma unroll
    for (int mi = 0; mi < 4; mi++)
#pragma unroll
        for (int ni = 0; ni < 4; ni++) acc[mi][ni] = (floatx4){0.f, 0.f, 0.f, 0.f};

    // prologue: tile 0 -> buffer 0
#pragma unroll
    for (int p = 0; p < 4; p++) {
        gload_lds16(Ab + (long)(p * 32 + srow) * lda + gch, &As[(p * 32 + w * 8) * 64]);
        gload_lds16(Wt + (long)(p * 32 + srow) * 768 + gch, &Bs[(p * 32 + w * 8) * 64]);
    }

    for (int kk = 0; kk < 12; kk++) {
        __syncthreads();   // drains loads for tile kk (issued last iter); fences buf reuse
        if (kk < 11) {
            const int k1 = (kk + 1) * 64;
            const int nb = ((kk + 1) & 1) * 8192;
#pragma unroll
            for (int p = 0; p < 4; p++) {
                gload_lds16(Ab + (long)(p * 32 + srow) * lda + k1 + gch,
                            &As[nb + (p * 32 + w * 8) * 64]);
                gload_lds16(Wt + (long)(p * 32 + srow) * 768 + k1 + gch,
                            &Bs[nb + (p * 32 + w * 8) * 64]);
            }
        }
        gemm_mfma_step(acc, As + (kk & 1) * 8192, Bs + (kk & 1) * 8192,
                       wm, wn, qr, lc, x7);
    }
    gemm_epilogue<CMODE, BIAS_MODE>(acc, bp, Cv, ldc, bm, bn, wm, wn, qr, lc);
}

// ---------------------------------------------------------------------------
// Single-buffered core for fp32 A (qkv only; small kernel, not worth dbuf).
// ---------------------------------------------------------------------------
template<int CMODE, int BIAS_MODE>
static __device__ __forceinline__ void gemm_core_f32(
    const float* __restrict__ A, const short* __restrict__ Wb,
    const float* __restrict__ bp, void* __restrict__ Cv,
    int lda, int ldc, int bm, int bn, short* As, short* Bs)
{
    GEMM_LANE_VARS
    const short* Wt = Wb + (long)(bn * 128) * 768;

    floatx4 acc[4][4];
#pragma unroll
    for (int mi = 0; mi < 4; mi++)
#pragma unroll
        for (int ni = 0; ni < 4; ni++) acc[mi][ni] = (floatx4){0.f, 0.f, 0.f, 0.f};

    for (int k0 = 0; k0 < 768; k0 += 64) {
        __syncthreads();
#pragma unroll
        for (int p = 0; p < 4; p++) {
            const int row = p * 32 + srow;
            const float* ap = A + (long)(bm * 128 + row) * lda + k0 + schunk * 8;
            floatx4 f0 = *(const floatx4*)ap;
            floatx4 f1 = *(const floatx4*)(ap + 4);
            *(short8*)&As[row * 64 + ((schunk ^ sx) << 3)] = f8_to_bf8(f0, f1);
            gload_lds16(Wt + (long)row * 768 + k0 + ((schunk ^ sx) << 3),
                        &Bs[(p * 32 + w * 8) * 64]);
        }
        __syncthreads();
        gemm_mfma_step(acc, As, Bs, wm, wn, qr, lc, x7);
    }
    gemm_epilogue<CMODE, BIAS_MODE>(acc, bp, Cv, ldc, bm, bn, wm, wn, qr, lc);
}

// qkv projections: grid (576). XCD k owns bm in [4k,4k+4); order bm->y->bn.
__global__ __launch_bounds__(256) void qkv_gemm(
    const float* q, const float* k, const float* v, const short* Wbf,
    const float* bq, const float* bk, const float* bv, short* outp)
{
    __shared__ short As[128 * 64];
    __shared__ short Bs[128 * 64];
    const int xcd = blockIdx.x & 7, slot = blockIdx.x >> 3;   // slot 0..71
    const int bm = xcd * 4 + slot / 18;
    const int rem = slot % 18, y = rem / 6, bn = rem % 6;
    const float* A    = (y == 0) ? q  : (y == 1) ? k  : v;
    const float* bias = (y == 0) ? bq : (y == 1) ? bk : bv;
    gemm_core_f32<0, 0>(A, Wbf + (long)y * 589824, bias, outp + (long)y * 3145728,
                        768, 768, bm, bn, As, Bs);
}

// mid GEMMs fused: grid (1728), dyn LDS 64 KB. XCD k owns z=(b,g)=k.
__global__ __launch_bounds__(256) void mid_gemm(
    const short* kproj, const short* vproj, const short* qproj, const short* Wbf,
    const float* bq_in, const float* bk_in, const float* bv_in,
    short* kiB, short* vtB, short* qiB)
{
    extern __shared__ short sm[];
    short* As = sm;             // 2 x 8192
    short* Bs = sm + 16384;     // 2 x 8192
    const int xcd = blockIdx.x & 7, slot = blockIdx.x >> 3;   // slot 0..215
    const int z = xcd, b = z >> 2, g = z & 3;
    if (slot < 96) {
        gemm_core_db<0, 0>(kproj + (long)b * 1572864, Wbf + (long)(7 + g) * 589824,
                           bk_in + g * 768, kiB + (long)z * 1572864,
                           768, 768, slot / 6, slot % 6, As, Bs);
    } else if (slot < 192) {
        const int s2 = slot - 96;   // vt[b,g,f,s] = Wv_in @ v_proj^T : M=768, N=2048
        gemm_core_db<0, 1>(Wbf + (long)(11 + g) * 589824, vproj + (long)b * 1572864,
                           bv_in + g * 768, vtB + (long)z * 1572864,
                           768, 2048, s2 / 16, s2 % 16, As, Bs);
    } else {
        const int s3 = slot - 192;  // qi: M=512, interleaved gather (token = t*4+g)
        gemm_core_db<0, 0>(qproj + (long)b * 1572864 + g * 768, Wbf + (long)(3 + g) * 589824,
                           bq_in + g * 768, qiB + (long)z * 393216,
                           3072, 768, s3 / 6, s3 % 6, As, Bs);
    }
}

// out projection: grid (192), dyn LDS 64 KB. fp32 C scattered (ldc=3072).
__global__ __launch_bounds__(256) void out_gemm(
    const short* ctxB, const short* Wbf, const float* bout, float* out)
{
    extern __shared__ short sm[];
    short* As = sm;
    short* Bs = sm + 16384;
    const int xcd = blockIdx.x & 7, slot = blockIdx.x >> 3;   // slot 0..23
    const int z = xcd, b = z >> 2, g = z & 3;
    gemm_core_db<2, 0>(ctxB + (long)z * 393216, Wbf + (long)(15 + g) * 589824,
                       bout + g * 768, out + (long)b * 1572864 + g * 768,
                       768, 3072, slot / 6, slot % 6, As, Bs);
}

// ---------------------------------------------------------------------------
// Flash attention (unchanged from R6). 1 WG = 64 q-rows of one (b,g,h).
// Double-buffered 64-wide K/V tiles; no-max softmax; MFMA ones-column l.
// blockIdx = tile*96 + head; 96 % 8 == 0 so a head's 8 tiles share an XCD.
// ---------------------------------------------------------------------------
__global__ __launch_bounds__(256) void attn_kernel(
    const short* __restrict__ qi, const short* __restrict__ ki,
    const short* __restrict__ vt, short* __restrict__ ctx)
{
    __shared__ short Kt[2][64 * 64];
    __shared__ short Vt[2][64 * 64];
    __shared__ short Ps[4][16 * 64];

    const int tid = threadIdx.x, lane = tid & 63, w = tid >> 6;
    const int qr = lane >> 4, lc = lane & 15, x7 = lc & 7;
    const int headid = blockIdx.x % 96;
    const int tile = blockIdx.x / 96;
    const int h = headid % 12, bg = headid / 12;

    const short* qp = qi + ((long)bg * 512 + tile * 64 + w * 16 + lc) * 768 + h * 64 + qr * 8;
    const short8 aq0 = *(const short8*)qp;
    const short8 aq1 = *(const short8*)(qp + 32);

    const short one = (lc == 0) ? (short)0x3F80 : (short)0;   // bf16 1.0
    const short8 onesv = (short8){one, one, one, one, one, one, one, one};

    floatx4 cacc[4], lacc = (floatx4){0.f, 0.f, 0.f, 0.f};
#pragma unroll
    for (int dc = 0; dc < 4; dc++) cacc[dc] = (floatx4){0.f, 0.f, 0.f, 0.f};

    const int srow = lane >> 3, schk = lane & 7, swz = schk ^ srow;
    const short* kgb = ki + ((long)bg * 2048) * 768 + h * 64;
    const short* vgb = vt + ((long)(bg * 768 + h * 64)) * 2048;

#pragma unroll
    for (int inst = 0; inst < 2; inst++) {
        const int rk = w * 16 + inst * 8 + srow;
        gload_lds16(kgb + (long)rk * 768 + swz * 8, &Kt[0][(w * 16 + inst * 8) * 64]);
        gload_lds16(vgb + (long)rk * 2048 + swz * 8, &Vt[0][(w * 16 + inst * 8) * 64]);
    }

    for (int it = 0; it < 32; it++) {
        const int cur = it & 1;
        __syncthreads();
        if (it < 31) {
            const int nxt = cur ^ 1, s0 = (it + 1) * 64;
#pragma unroll
            for (int inst = 0; inst < 2; inst++) {
                const int rk = w * 16 + inst * 8 + srow;
                gload_lds16(kgb + (long)(s0 + rk) * 768 + swz * 8,
                            &Kt[nxt][(w * 16 + inst * 8) * 64]);
                gload_lds16(vgb + (long)rk * 2048 + s0 + swz * 8,
                            &Vt[nxt][(w * 16 + inst * 8) * 64]);
            }
        }

        const short* Kb = &Kt[cur][0];
        const short* Vb = &Vt[cur][0];

        floatx4 sv[4];
#pragma unroll
        for (int ss = 0; ss < 4; ss++) {
            const short* kr = Kb + (ss * 16 + lc) * 64;
            short8 b0 = *(const short8*)(kr + ((qr ^ x7) << 3));
            short8 b1 = *(const short8*)(kr + (((4 + qr) ^ x7) << 3));
            floatx4 t = (floatx4){0.f, 0.f, 0.f, 0.f};
            t = __builtin_amdgcn_mfma_f32_16x16x32_bf16(aq0, b0, t, 0, 0, 0);
            t = __builtin_amdgcn_mfma_f32_16x16x32_bf16(aq1, b1, t, 0, 0, 0);
            sv[ss] = t;
        }

        // p = exp2(s * 0.125*log2e) -> P scratch (swizzled)
        short* ps = &Ps[w][0];
#pragma unroll
        for (int ss = 0; ss < 4; ss++) {
            const int cch = ss * 2 + (lc >> 3);
#pragma unroll
            for (int r = 0; r < 4; r++) {
                const int m = qr * 4 + r;
                ps[m * 64 + ((cch ^ (m & 7)) << 3) + x7] =
                    f2bf(__builtin_amdgcn_exp2f(sv[ss][r] * 0.18033688f));
            }
        }
        asm volatile("s_waitcnt lgkmcnt(0)" ::: "memory");
        const short8 ap0 = *(const short8*)&ps[lc * 64 + ((qr ^ x7) << 3)];
        const short8 ap1 = *(const short8*)&ps[lc * 64 + (((4 + qr) ^ x7) << 3)];

        lacc = __builtin_amdgcn_mfma_f32_16x16x32_bf16(ap0, onesv, lacc, 0, 0, 0);
        lacc = __builtin_amdgcn_mfma_f32_16x16x32_bf16(ap1, onesv, lacc, 0, 0, 0);
#pragma unroll
        for (int dc = 0; dc < 4; dc++) {
            const short* vr = Vb + (dc * 16 + lc) * 64;
            short8 bv0 = *(const short8*)(vr + ((qr ^ x7) << 3));
            short8 bv1 = *(const short8*)(vr + (((4 + qr) ^ x7) << 3));
            cacc[dc] = __builtin_amdgcn_mfma_f32_16x16x32_bf16(ap0, bv0, cacc[dc], 0, 0, 0);
            cacc[dc] = __builtin_amdgcn_mfma_f32_16x16x32_bf16(ap1, bv1, cacc[dc], 0, 0, 0);
        }
    }

    float linv[4];
#pragma unroll
    for (int r = 0; r < 4; r++)
        linv[r] = 1.f / __shfl(lacc[r], lane & 48);
    short* cp = ctx + ((long)bg * 512 + tile * 64 + w * 16) * 768 + h * 64;
#pragma unroll
    for (int dc = 0; dc < 4; dc++)
#pragma unroll
        for (int r = 0; r < 4; r++)
            cp[(qr * 4 + r) * 768 + dc * 16 + lc] = f2bf(cacc[dc][r] * linv[r]);
}

// ---------------------------------------------------------------------------
extern "C" void kernel_launch(void* const* d_in, const int* in_sizes, int n_in,
                              void* d_out, int out_size, void* d_ws, size_t ws_size,
                              hipStream_t stream) {
    const float* query = (const float*)d_in[0];
    const float* key   = (const float*)d_in[1];
    const float* value = (const float*)d_in[2];
    const float* Wqg = (const float*)d_in[3];  const float* bqg = (const float*)d_in[4];
    const float* Wk  = (const float*)d_in[5];  const float* bk  = (const float*)d_in[6];
    const float* Wv  = (const float*)d_in[7];  const float* bv  = (const float*)d_in[8];
    const float* Wq_in = (const float*)d_in[9];  const float* bq_in = (const float*)d_in[10];
    const float* Wk_in = (const float*)d_in[11]; const float* bk_in = (const float*)d_in[12];
    const float* Wv_in = (const float*)d_in[13]; const float* bv_in = (const float*)d_in[14];
    const float* Wout  = (const float*)d_in[15]; const float* bout  = (const float*)d_in[16];
    float* out = (float*)d_out;

    // workspace (shorts), ~98 MB:
    short* ws     = (short*)d_ws;
    short* Wbf    = ws;                  // [0, 11206656)
    short* q_proj = ws + 11206656L;      // q | k | v, 3 x 3145728
    short* k_proj = ws + 14352384L;
    short* v_proj = ws + 17498112L;
    short* qiB    = ws + 20643840L;      // 3145728
    short* vtB    = ws + 23789568L;      // 12582912
    short* kiB    = ws + 36372480L;      // 12582912, end 48955392
    short* ctxB   = ws + 11206656L;      // aliases q-slice (dead after mid_gemm)

    dim3 blk(256);

    cast_w<<<dim3(5472), blk, 0, stream>>>(
        Wqg, Wk, Wv, Wq_in, Wk_in, Wv_in, Wout, Wbf);

    qkv_gemm<<<dim3(576), blk, 0, stream>>>(
        query, key, value, Wbf, bqg, bk, bv, q_proj);

    mid_gemm<<<dim3(1728), blk, 65536, stream>>>(
        k_proj, v_proj, q_proj, Wbf, bq_in, bk_in, bv_in, kiB, vtB, qiB);

    attn_kernel<<<dim3(768), blk, 0, stream>>>(qiB, kiB, vtB, ctxB);

    out_gemm<<<dim3(192), blk, 65536, stream>>>(ctxB, Wbf, bout, out);
}